// Round 1
// baseline (1397.343 us; speedup 1.0000x reference)
//
#include <hip/hip_runtime.h>
#include <hip/hip_bf16.h>
#include <stdint.h>

#define NTOK 8192
#define NE 8
#define DIN 1024
#define DH 4096
#define DOUT 1024

typedef __bf16 bf16;
typedef __bf16 bf16_8 __attribute__((ext_vector_type(8)));
typedef __bf16 bf16_4 __attribute__((ext_vector_type(4)));
typedef float f32_4 __attribute__((ext_vector_type(4)));

__device__ __forceinline__ void gl_lds16(const void* g, void* l) {
  __builtin_amdgcn_global_load_lds(
      (const __attribute__((address_space(1))) unsigned int*)g,
      (__attribute__((address_space(3))) unsigned int*)l, 16, 0, 0);
}

// ---------------- gating: fp32 logits, top-2, softmax, expert lists ----------
__global__ void gate_kernel(const float* __restrict__ x, const float* __restrict__ Wg,
                            const float* __restrict__ bg,
                            int* counts, int* topi, float* topw, int* pos) {
  int t = blockIdx.x * 4 + (threadIdx.x >> 6);
  int lane = threadIdx.x & 63;
  float acc[NE];
#pragma unroll
  for (int e = 0; e < NE; e++) acc[e] = 0.f;
  const float* xr = x + (size_t)t * DIN;
#pragma unroll
  for (int i = 0; i < DIN / 64; i++) {
    float xv = xr[lane + 64 * i];
    const float4* wr = (const float4*)(Wg + (size_t)(lane + 64 * i) * NE);
    float4 w0 = wr[0], w1 = wr[1];
    acc[0] += xv * w0.x; acc[1] += xv * w0.y; acc[2] += xv * w0.z; acc[3] += xv * w0.w;
    acc[4] += xv * w1.x; acc[5] += xv * w1.y; acc[6] += xv * w1.z; acc[7] += xv * w1.w;
  }
#pragma unroll
  for (int off = 32; off > 0; off >>= 1)
#pragma unroll
    for (int e = 0; e < NE; e++) acc[e] += __shfl_xor(acc[e], off, 64);
  if (lane == 0) {
    float lg[NE];
#pragma unroll
    for (int e = 0; e < NE; e++) lg[e] = acc[e] + bg[e];
    int i0 = 0; float v0 = lg[0];
#pragma unroll
    for (int e = 1; e < NE; e++) if (lg[e] > v0) { v0 = lg[e]; i0 = e; }
    int i1 = -1; float v1 = -3.0e38f;
#pragma unroll
    for (int e = 0; e < NE; e++) if (e != i0 && lg[e] > v1) { v1 = lg[e]; i1 = e; }
    float ex = expf(v1 - v0);
    float w0 = 1.f / (1.f + ex);
    float w1 = ex / (1.f + ex);
    int p0 = atomicAdd(&counts[i0], 1);
    int p1 = atomicAdd(&counts[i1], 1);
    topi[2 * t] = i0; topi[2 * t + 1] = i1;
    topw[2 * t] = w0; topw[2 * t + 1] = w1;
    pos[2 * t] = p0; pos[2 * t + 1] = p1;
  }
}

__global__ void scan_kernel(const int* counts, int* offsets) {
  if (threadIdx.x == 0) {
    int s = 0;
    for (int e = 0; e < NE; e++) { offsets[e] = s; s += counts[e]; }
  }
}

__global__ void pack_kernel(const int* __restrict__ topi, const float* __restrict__ topw,
                            const int* __restrict__ pos, const int* __restrict__ offsets,
                            int* __restrict__ tok_list, float* __restrict__ w_list) {
  int i = blockIdx.x * 256 + threadIdx.x;  // < 16384
  int e = topi[i];
  int slot = offsets[e] + pos[i];
  tok_list[slot] = i >> 1;
  w_list[slot] = topw[i];
}

// ---------------- x fp32 -> bf16 --------------------------------------------
__global__ void cvtx_kernel(const float* __restrict__ x, bf16* __restrict__ xb) {
  size_t i = ((size_t)blockIdx.x * 256 + threadIdx.x) * 8;
  float4 a = *(const float4*)(x + i);
  float4 b = *(const float4*)(x + i + 4);
  bf16_8 o;
  o[0] = (bf16)a.x; o[1] = (bf16)a.y; o[2] = (bf16)a.z; o[3] = (bf16)a.w;
  o[4] = (bf16)b.x; o[5] = (bf16)b.y; o[6] = (bf16)b.z; o[7] = (bf16)b.w;
  *(bf16_8*)(xb + i) = o;
}

// ---------------- out init: out[t] = w0*b2[e0] + w1*b2[e1] ------------------
__global__ void init_out_kernel(const int* __restrict__ topi, const float* __restrict__ topw,
                                const float* __restrict__ b2, float* __restrict__ out) {
  int t = blockIdx.x;
  int c = threadIdx.x * 4;
  int e0 = topi[2 * t], e1 = topi[2 * t + 1];
  float w0 = topw[2 * t], w1 = topw[2 * t + 1];
  float4 v0 = *(const float4*)(b2 + (size_t)e0 * DOUT + c);
  float4 v1 = *(const float4*)(b2 + (size_t)e1 * DOUT + c);
  float4 o;
  o.x = w0 * v0.x + w1 * v1.x;
  o.y = w0 * v0.y + w1 * v1.y;
  o.z = w0 * v0.z + w1 * v1.z;
  o.w = w0 * v0.w + w1 * v1.w;
  *(float4*)(out + (size_t)t * DOUT + c) = o;
}

// ---------------- transpose + fp32->bf16: dst[n][k] = src[k][n] -------------
__global__ void tcvt_kernel(const float* __restrict__ src, bf16* __restrict__ dst,
                            int src_ld, long long src_es, int dst_ld, long long dst_es) {
  __shared__ bf16 tile[32][33];
  const float* s = src + blockIdx.z * src_es + (size_t)(blockIdx.x * 32) * src_ld + blockIdx.y * 32;
  bf16* d = dst + blockIdx.z * dst_es + (size_t)(blockIdx.y * 32) * dst_ld + blockIdx.x * 32;
  int tid = threadIdx.x;
  int r = tid >> 3, c4 = (tid & 7) * 4;
  float4 v = *(const float4*)(s + (size_t)r * src_ld + c4);
  tile[r][c4] = (bf16)v.x; tile[r][c4 + 1] = (bf16)v.y;
  tile[r][c4 + 2] = (bf16)v.z; tile[r][c4 + 3] = (bf16)v.w;
  __syncthreads();
  int n = tid >> 3, k4 = (tid & 7) * 4;
  bf16_4 o;
  o[0] = tile[k4][n]; o[1] = tile[k4 + 1][n]; o[2] = tile[k4 + 2][n]; o[3] = tile[k4 + 3][n];
  *(bf16_4*)(d + (size_t)n * dst_ld + k4) = o;
}

// ---------------- GEMM1: h = relu(gather(xb) @ W1t^T + b1) ------------------
// tiles: BM=128, BN=128, BK=32; 256 thr = 4 waves in 2x2; mfma 16x16x32 bf16
__global__ __launch_bounds__(256) void gemm1_kernel(
    const bf16* __restrict__ xb, const bf16* __restrict__ W1t,
    const float* __restrict__ b1, const int* __restrict__ counts,
    const int* __restrict__ offsets, const int* __restrict__ tok_list,
    bf16* __restrict__ h, int hchunk, int hc0) {
  int e = blockIdx.y;
  int ne = counts[e];
  int m0 = blockIdx.x * 128;
  if (m0 >= ne) return;
  int off = offsets[e];
  int n0 = blockIdx.z * 128;

  __shared__ bf16 ldsA[128 * 32];
  __shared__ bf16 ldsB[128 * 32];

  int tid = threadIdx.x;
  int w = tid >> 6, lane = tid & 63;

  const bf16* gA[2]; const bf16* gB[2];
  bf16* lA[2]; bf16* lB[2];
#pragma unroll
  for (int j = 0; j < 2; j++) {
    int seg = w * 2 + j;
    int row = seg * 16 + (lane >> 2);
    int slot = off + m0 + row;
    int smax = off + ne - 1;
    if (slot > smax) slot = smax;           // clamp tail rows to a valid token
    int tok = tok_list[slot];
    gA[j] = xb + (size_t)tok * DIN + (lane & 3) * 8;
    lA[j] = ldsA + seg * 512;               // wave-uniform base; HW adds lane*16B
    gB[j] = W1t + ((size_t)e * hchunk + n0 + row) * DIN + (lane & 3) * 8;
    lB[j] = ldsB + seg * 512;
  }

  f32_4 acc[4][4];
#pragma unroll
  for (int i = 0; i < 4; i++)
#pragma unroll
    for (int j = 0; j < 4; j++) acc[i][j] = (f32_4){0.f, 0.f, 0.f, 0.f};

  int wm = w & 1, wn = w >> 1;
  int lr = lane & 15, quad = lane >> 4;

  for (int kt = 0; kt < DIN / 32; kt++) {
#pragma unroll
    for (int j = 0; j < 2; j++) {
      gl_lds16(gA[j], lA[j]);
      gl_lds16(gB[j], lB[j]);
    }
    gA[0] += 32; gA[1] += 32; gB[0] += 32; gB[1] += 32;
    __syncthreads();
    bf16_8 af[4], bfr[4];
#pragma unroll
    for (int mt = 0; mt < 4; mt++)
      af[mt] = *(const bf16_8*)(ldsA + (wm * 64 + mt * 16 + lr) * 32 + quad * 8);
#pragma unroll
    for (int nt = 0; nt < 4; nt++)
      bfr[nt] = *(const bf16_8*)(ldsB + (wn * 64 + nt * 16 + lr) * 32 + quad * 8);
#pragma unroll
    for (int mt = 0; mt < 4; mt++)
#pragma unroll
      for (int nt = 0; nt < 4; nt++)
        acc[mt][nt] = __builtin_amdgcn_mfma_f32_16x16x32_bf16(af[mt], bfr[nt], acc[mt][nt], 0, 0, 0);
    __syncthreads();
  }

#pragma unroll
  for (int nt = 0; nt < 4; nt++) {
    int cloc = wn * 64 + nt * 16 + lr;
    int c = n0 + cloc;                       // col within chunk
    float bias = b1[(size_t)e * DH + hc0 + c];
#pragma unroll
    for (int mt = 0; mt < 4; mt++) {
#pragma unroll
      for (int r2 = 0; r2 < 4; r2++) {
        int row = wm * 64 + mt * 16 + quad * 4 + r2;
        if (m0 + row < ne) {
          float v = acc[mt][nt][r2] + bias;
          v = v > 0.f ? v : 0.f;
          h[(size_t)(off + m0 + row) * hchunk + c] = (bf16)v;
        }
      }
    }
  }
}

// ---------------- GEMM2: out[tok] += w * (h @ W2t^T) ------------------------
__global__ __launch_bounds__(256) void gemm2_kernel(
    const bf16* __restrict__ h, const bf16* __restrict__ W2t,
    const int* __restrict__ counts, const int* __restrict__ offsets,
    const int* __restrict__ tok_list, const float* __restrict__ w_list,
    float* __restrict__ out, int hchunk) {
  int e = blockIdx.y;
  int ne = counts[e];
  int m0 = blockIdx.x * 128;
  if (m0 >= ne) return;
  int off = offsets[e];
  int n0 = blockIdx.z * 128;

  __shared__ bf16 ldsA[128 * 32];
  __shared__ bf16 ldsB[128 * 32];

  int tid = threadIdx.x;
  int w = tid >> 6, lane = tid & 63;

  const bf16* gA[2]; const bf16* gB[2];
  bf16* lA[2]; bf16* lB[2];
#pragma unroll
  for (int j = 0; j < 2; j++) {
    int seg = w * 2 + j;
    int row = seg * 16 + (lane >> 2);
    gA[j] = h + (size_t)(off + m0 + row) * hchunk + (lane & 3) * 8;  // h padded +128 rows
    lA[j] = ldsA + seg * 512;
    gB[j] = W2t + ((size_t)e * DOUT + n0 + row) * hchunk + (lane & 3) * 8;
    lB[j] = ldsB + seg * 512;
  }

  f32_4 acc[4][4];
#pragma unroll
  for (int i = 0; i < 4; i++)
#pragma unroll
    for (int j = 0; j < 4; j++) acc[i][j] = (f32_4){0.f, 0.f, 0.f, 0.f};

  int wm = w & 1, wn = w >> 1;
  int lr = lane & 15, quad = lane >> 4;

  for (int kt = 0; kt < hchunk / 32; kt++) {
#pragma unroll
    for (int j = 0; j < 2; j++) {
      gl_lds16(gA[j], lA[j]);
      gl_lds16(gB[j], lB[j]);
    }
    gA[0] += 32; gA[1] += 32; gB[0] += 32; gB[1] += 32;
    __syncthreads();
    bf16_8 af[4], bfr[4];
#pragma unroll
    for (int mt = 0; mt < 4; mt++)
      af[mt] = *(const bf16_8*)(ldsA + (wm * 64 + mt * 16 + lr) * 32 + quad * 8);
#pragma unroll
    for (int nt = 0; nt < 4; nt++)
      bfr[nt] = *(const bf16_8*)(ldsB + (wn * 64 + nt * 16 + lr) * 32 + quad * 8);
#pragma unroll
    for (int mt = 0; mt < 4; mt++)
#pragma unroll
      for (int nt = 0; nt < 4; nt++)
        acc[mt][nt] = __builtin_amdgcn_mfma_f32_16x16x32_bf16(af[mt], bfr[nt], acc[mt][nt], 0, 0, 0);
    __syncthreads();
  }

#pragma unroll
  for (int mt = 0; mt < 4; mt++) {
#pragma unroll
    for (int r2 = 0; r2 < 4; r2++) {
      int row = wm * 64 + mt * 16 + quad * 4 + r2;
      if (m0 + row < ne) {
        int slot = off + m0 + row;
        int t = tok_list[slot];
        float wgt = w_list[slot];
        float* orow = out + (size_t)t * DOUT;
#pragma unroll
        for (int nt = 0; nt < 4; nt++) {
          int c = n0 + wn * 64 + nt * 16 + lr;
          atomicAdd(orow + c, wgt * acc[mt][nt][r2]);
        }
      }
    }
  }
}

// ---------------- host ------------------------------------------------------
extern "C" void kernel_launch(void* const* d_in, const int* in_sizes, int n_in,
                              void* d_out, int out_size, void* d_ws, size_t ws_size,
                              hipStream_t stream) {
  const float* x  = (const float*)d_in[0];
  const float* Wg = (const float*)d_in[1];
  const float* bg = (const float*)d_in[2];
  const float* W1 = (const float*)d_in[3];
  const float* b1 = (const float*)d_in[4];
  const float* W2 = (const float*)d_in[5];
  const float* b2 = (const float*)d_in[6];
  float* out = (float*)d_out;

  char* p = (char*)d_ws;
  int*   counts   = (int*)p;   p += 256;
  int*   offsets  = (int*)p;   p += 256;
  int*   topi     = (int*)p;   p += 16384 * 4;
  float* topw     = (float*)p; p += 16384 * 4;
  int*   pos      = (int*)p;   p += 16384 * 4;
  int*   tok_list = (int*)p;   p += 16384 * 4;
  float* w_list   = (float*)p; p += 16384 * 4;
  bf16*  xb       = (bf16*)p;  p += (size_t)NTOK * DIN * 2;

  size_t fixedBytes = (size_t)(p - (char*)d_ws);
  // per-hchunk bytes: h (16384+128 rows) + W1t + W2t = 33024 + 16384 + 16384 = 65792
  int hchunk = 2048;
  while (hchunk > 128 && fixedBytes + (size_t)hchunk * 65792 > ws_size) hchunk >>= 1;

  bf16* W1t  = (bf16*)p; p += (size_t)NE * hchunk * DIN * 2;
  bf16* W2t  = (bf16*)p; p += (size_t)NE * DOUT * hchunk * 2;
  bf16* hbuf = (bf16*)p; p += (size_t)(16384 + 128) * hchunk * 2;

  hipMemsetAsync(counts, 0, 32, stream);
  gate_kernel<<<NTOK / 4, 256, 0, stream>>>(x, Wg, bg, counts, topi, topw, pos);
  cvtx_kernel<<<(NTOK * DIN) / (8 * 256), 256, 0, stream>>>(x, xb);
  scan_kernel<<<1, 64, 0, stream>>>(counts, offsets);
  pack_kernel<<<64, 256, 0, stream>>>(topi, topw, pos, offsets, tok_list, w_list);
  init_out_kernel<<<NTOK, 256, 0, stream>>>(topi, topw, b2, out);

  int nchunks = DH / hchunk;
  for (int c = 0; c < nchunks; c++) {
    int hc0 = c * hchunk;
    // W1t[e][n][k] = W1[e][k][hc0+n]  (k rows: 1024, n cols: hchunk)
    tcvt_kernel<<<dim3(DIN / 32, hchunk / 32, NE), 256, 0, stream>>>(
        W1 + hc0, W1t, DH, (long long)DIN * DH, DIN, (long long)hchunk * DIN);
    // W2t[e][o][hk] = W2[e][hc0+hk][o] (hk rows: hchunk, o cols: 1024)
    tcvt_kernel<<<dim3(hchunk / 32, DOUT / 32, NE), 256, 0, stream>>>(
        W2 + (size_t)hc0 * DOUT, W2t, DOUT, (long long)DH * DOUT, hchunk, (long long)DOUT * hchunk);
    gemm1_kernel<<<dim3(64, NE, hchunk / 128), 256, 0, stream>>>(
        xb, W1t, b1, counts, offsets, tok_list, hbuf, hchunk, hc0);
    gemm2_kernel<<<dim3(64, NE, DOUT / 128), 256, 0, stream>>>(
        hbuf, W2t, counts, offsets, tok_list, w_list, out, hchunk);
  }
}

// Round 2
// 1073.243 us; speedup vs baseline: 1.3020x; 1.3020x over previous
//
#include <hip/hip_runtime.h>
#include <hip/hip_bf16.h>
#include <stdint.h>

#define NTOK 8192
#define NE 8
#define DIN 1024
#define DH 4096
#define DOUT 1024
#define MAXMB 135  // max total m-blocks: 16384/128 + 7 partial tails

typedef __bf16 bf16;
typedef __bf16 bf16_8 __attribute__((ext_vector_type(8)));
typedef __bf16 bf16_4 __attribute__((ext_vector_type(4)));
typedef float f32_4 __attribute__((ext_vector_type(4)));

__device__ __forceinline__ void gl_lds16(const void* g, void* l) {
  __builtin_amdgcn_global_load_lds(
      (const __attribute__((address_space(1))) unsigned int*)g,
      (__attribute__((address_space(3))) unsigned int*)l, 16, 0, 0);
}

// ---------------- gating: fp32 logits, top-2, softmax, expert lists ----------
__global__ void gate_kernel(const float* __restrict__ x, const float* __restrict__ Wg,
                            const float* __restrict__ bg,
                            int* counts, int* topi, float* topw, int* pos) {
  int t = blockIdx.x * 4 + (threadIdx.x >> 6);
  int lane = threadIdx.x & 63;
  float acc[NE];
#pragma unroll
  for (int e = 0; e < NE; e++) acc[e] = 0.f;
  const float* xr = x + (size_t)t * DIN;
#pragma unroll
  for (int i = 0; i < DIN / 64; i++) {
    float xv = xr[lane + 64 * i];
    const float4* wr = (const float4*)(Wg + (size_t)(lane + 64 * i) * NE);
    float4 w0 = wr[0], w1 = wr[1];
    acc[0] += xv * w0.x; acc[1] += xv * w0.y; acc[2] += xv * w0.z; acc[3] += xv * w0.w;
    acc[4] += xv * w1.x; acc[5] += xv * w1.y; acc[6] += xv * w1.z; acc[7] += xv * w1.w;
  }
#pragma unroll
  for (int off = 32; off > 0; off >>= 1)
#pragma unroll
    for (int e = 0; e < NE; e++) acc[e] += __shfl_xor(acc[e], off, 64);
  if (lane == 0) {
    float lg[NE];
#pragma unroll
    for (int e = 0; e < NE; e++) lg[e] = acc[e] + bg[e];
    int i0 = 0; float v0 = lg[0];
#pragma unroll
    for (int e = 1; e < NE; e++) if (lg[e] > v0) { v0 = lg[e]; i0 = e; }
    int i1 = -1; float v1 = -3.0e38f;
#pragma unroll
    for (int e = 0; e < NE; e++) if (e != i0 && lg[e] > v1) { v1 = lg[e]; i1 = e; }
    float ex = expf(v1 - v0);
    float w0 = 1.f / (1.f + ex);
    float w1 = ex / (1.f + ex);
    int p0 = atomicAdd(&counts[i0], 1);
    int p1 = atomicAdd(&counts[i1], 1);
    topi[2 * t] = i0; topi[2 * t + 1] = i1;
    topw[2 * t] = w0; topw[2 * t + 1] = w1;
    pos[2 * t] = p0; pos[2 * t + 1] = p1;
  }
}

// offsets[e]: token-slot prefix; mblk_off[e]: m-block prefix (for grid compaction)
__global__ void scan_kernel(const int* counts, int* offsets, int* mblk_off) {
  if (threadIdx.x == 0) {
    int s = 0, b = 0;
    for (int e = 0; e < NE; e++) {
      offsets[e] = s; mblk_off[e] = b;
      s += counts[e]; b += (counts[e] + 127) >> 7;
    }
    mblk_off[NE] = b;
  }
}

__global__ void pack_kernel(const int* __restrict__ topi, const float* __restrict__ topw,
                            const int* __restrict__ pos, const int* __restrict__ offsets,
                            int* __restrict__ tok_list, float* __restrict__ w_list) {
  int i = blockIdx.x * 256 + threadIdx.x;  // < 16384
  int e = topi[i];
  int slot = offsets[e] + pos[i];
  tok_list[slot] = i >> 1;
  w_list[slot] = topw[i];
}

// ---------------- x fp32 -> bf16 --------------------------------------------
__global__ void cvtx_kernel(const float* __restrict__ x, bf16* __restrict__ xb) {
  size_t i = ((size_t)blockIdx.x * 256 + threadIdx.x) * 8;
  float4 a = *(const float4*)(x + i);
  float4 b = *(const float4*)(x + i + 4);
  bf16_8 o;
  o[0] = (bf16)a.x; o[1] = (bf16)a.y; o[2] = (bf16)a.z; o[3] = (bf16)a.w;
  o[4] = (bf16)b.x; o[5] = (bf16)b.y; o[6] = (bf16)b.z; o[7] = (bf16)b.w;
  *(bf16_8*)(xb + i) = o;
}

// ---------------- out init: out[t] = w0*b2[e0] + w1*b2[e1] ------------------
__global__ void init_out_kernel(const int* __restrict__ topi, const float* __restrict__ topw,
                                const float* __restrict__ b2, float* __restrict__ out) {
  int t = blockIdx.x;
  int c = threadIdx.x * 4;
  int e0 = topi[2 * t], e1 = topi[2 * t + 1];
  float w0 = topw[2 * t], w1 = topw[2 * t + 1];
  float4 v0 = *(const float4*)(b2 + (size_t)e0 * DOUT + c);
  float4 v1 = *(const float4*)(b2 + (size_t)e1 * DOUT + c);
  float4 o;
  o.x = w0 * v0.x + w1 * v1.x;
  o.y = w0 * v0.y + w1 * v1.y;
  o.z = w0 * v0.z + w1 * v1.z;
  o.w = w0 * v0.w + w1 * v1.w;
  *(float4*)(out + (size_t)t * DOUT + c) = o;
}

// ---------------- transpose + fp32->bf16: dst[n][k] = src[k][n] -------------
__global__ void tcvt_kernel(const float* __restrict__ src, bf16* __restrict__ dst,
                            int src_ld, long long src_es, int dst_ld, long long dst_es) {
  __shared__ bf16 tile[32][33];
  const float* s = src + blockIdx.z * src_es + (size_t)(blockIdx.x * 32) * src_ld + blockIdx.y * 32;
  bf16* d = dst + blockIdx.z * dst_es + (size_t)(blockIdx.y * 32) * dst_ld + blockIdx.x * 32;
  int tid = threadIdx.x;
  int r = tid >> 3, c4 = (tid & 7) * 4;
  float4 v = *(const float4*)(s + (size_t)r * src_ld + c4);
  tile[r][c4] = (bf16)v.x; tile[r][c4 + 1] = (bf16)v.y;
  tile[r][c4 + 2] = (bf16)v.z; tile[r][c4 + 3] = (bf16)v.w;
  __syncthreads();
  int n = tid >> 3, k4 = (tid & 7) * 4;
  bf16_4 o;
  o[0] = tile[k4][n]; o[1] = tile[k4 + 1][n]; o[2] = tile[k4 + 2][n]; o[3] = tile[k4 + 3][n];
  *(bf16_4*)(d + (size_t)n * dst_ld + k4) = o;
}

// Bank-conflict swizzle: within each 64B LDS row (4 x 16B cols), col' = col ^ ((row&15)>>1) & 3.
// Gather side: lane l in a segment stages global col ((l&3)^(l>>3))&3 of row l>>2,
// keeping lane->LDS contiguity for global_load_lds.

// ---------------- GEMM1: h = relu(gather(xb) @ W1t^T + b1) ------------------
// tiles: BM=128, BN=128, BK=32; 256 thr = 4 waves in 2x2; mfma 16x16x32 bf16
__global__ __launch_bounds__(256) void gemm1_kernel(
    const bf16* __restrict__ xb, const bf16* __restrict__ W1t,
    const float* __restrict__ b1, const int* __restrict__ counts,
    const int* __restrict__ offsets, const int* __restrict__ mblk_off,
    const int* __restrict__ tok_list,
    bf16* __restrict__ h, int hchunk, int hc0) {
  int mb = blockIdx.y;
  if (mb >= mblk_off[NE]) return;
  int e = 0;
  while (mb >= mblk_off[e + 1]) e++;
  int ne = counts[e];
  int m0 = (mb - mblk_off[e]) * 128;
  int off = offsets[e];
  int n0 = blockIdx.x * 128;

  __shared__ bf16 ldsA[128 * 32];
  __shared__ bf16 ldsB[128 * 32];

  int tid = threadIdx.x;
  int w = tid >> 6, lane = tid & 63;
  int scol = (((lane & 3) ^ (lane >> 3)) & 3) * 8;  // swizzled 16B col for staging

  const bf16* gA[2]; const bf16* gB[2];
  bf16* lA[2]; bf16* lB[2];
#pragma unroll
  for (int j = 0; j < 2; j++) {
    int seg = w * 2 + j;
    int row = seg * 16 + (lane >> 2);
    int slot = off + m0 + row;
    int smax = off + ne - 1;
    if (slot > smax) slot = smax;           // clamp tail rows to a valid token
    int tok = tok_list[slot];
    gA[j] = xb + (size_t)tok * DIN + scol;
    lA[j] = ldsA + seg * 512;               // wave-uniform base; HW adds lane*16B
    gB[j] = W1t + ((size_t)e * hchunk + n0 + row) * DIN + scol;
    lB[j] = ldsB + seg * 512;
  }

  f32_4 acc[4][4];
#pragma unroll
  for (int i = 0; i < 4; i++)
#pragma unroll
    for (int j = 0; j < 4; j++) acc[i][j] = (f32_4){0.f, 0.f, 0.f, 0.f};

  int wm = w & 1, wn = w >> 1;
  int lr = lane & 15, quad = lane >> 4;
  int rq[4];
#pragma unroll
  for (int q = 0; q < 4; q++) rq[q] = ((quad ^ (lr >> 1)) & 3) * 8;  // same for all, but keep form
  int rcol = ((quad ^ (lr >> 1)) & 3) * 8;

  for (int kt = 0; kt < DIN / 32; kt++) {
#pragma unroll
    for (int j = 0; j < 2; j++) {
      gl_lds16(gA[j], lA[j]);
      gl_lds16(gB[j], lB[j]);
    }
    gA[0] += 32; gA[1] += 32; gB[0] += 32; gB[1] += 32;
    __syncthreads();
    bf16_8 af[4], bfr[4];
#pragma unroll
    for (int mt = 0; mt < 4; mt++)
      af[mt] = *(const bf16_8*)(ldsA + (wm * 64 + mt * 16 + lr) * 32 + rcol);
#pragma unroll
    for (int nt = 0; nt < 4; nt++)
      bfr[nt] = *(const bf16_8*)(ldsB + (wn * 64 + nt * 16 + lr) * 32 + rcol);
#pragma unroll
    for (int mt = 0; mt < 4; mt++)
#pragma unroll
      for (int nt = 0; nt < 4; nt++)
        acc[mt][nt] = __builtin_amdgcn_mfma_f32_16x16x32_bf16(af[mt], bfr[nt], acc[mt][nt], 0, 0, 0);
    __syncthreads();
  }

#pragma unroll
  for (int nt = 0; nt < 4; nt++) {
    int cloc = wn * 64 + nt * 16 + lr;
    int c = n0 + cloc;                       // col within chunk
    float bias = b1[(size_t)e * DH + hc0 + c];
#pragma unroll
    for (int mt = 0; mt < 4; mt++) {
#pragma unroll
      for (int r2 = 0; r2 < 4; r2++) {
        int row = wm * 64 + mt * 16 + quad * 4 + r2;
        if (m0 + row < ne) {
          float v = acc[mt][nt][r2] + bias;
          v = v > 0.f ? v : 0.f;
          h[(size_t)(off + m0 + row) * hchunk + c] = (bf16)v;
        }
      }
    }
  }
}

// ---------------- GEMM2: out[tok] += w * (h @ W2t^T) ------------------------
__global__ __launch_bounds__(256) void gemm2_kernel(
    const bf16* __restrict__ h, const bf16* __restrict__ W2t,
    const int* __restrict__ counts, const int* __restrict__ offsets,
    const int* __restrict__ mblk_off, const int* __restrict__ tok_list,
    const float* __restrict__ w_list,
    float* __restrict__ out, int hchunk) {
  int mb = blockIdx.y;
  if (mb >= mblk_off[NE]) return;
  int e = 0;
  while (mb >= mblk_off[e + 1]) e++;
  int ne = counts[e];
  int m0 = (mb - mblk_off[e]) * 128;
  int off = offsets[e];
  int n0 = blockIdx.x * 128;

  __shared__ bf16 ldsA[128 * 32];
  __shared__ bf16 ldsB[128 * 32];

  int tid = threadIdx.x;
  int w = tid >> 6, lane = tid & 63;
  int scol = (((lane & 3) ^ (lane >> 3)) & 3) * 8;

  const bf16* gA[2]; const bf16* gB[2];
  bf16* lA[2]; bf16* lB[2];
#pragma unroll
  for (int j = 0; j < 2; j++) {
    int seg = w * 2 + j;
    int row = seg * 16 + (lane >> 2);
    gA[j] = h + (size_t)(off + m0 + row) * hchunk + scol;  // h padded +128 rows
    lA[j] = ldsA + seg * 512;
    gB[j] = W2t + ((size_t)e * DOUT + n0 + row) * hchunk + scol;
    lB[j] = ldsB + seg * 512;
  }

  f32_4 acc[4][4];
#pragma unroll
  for (int i = 0; i < 4; i++)
#pragma unroll
    for (int j = 0; j < 4; j++) acc[i][j] = (f32_4){0.f, 0.f, 0.f, 0.f};

  int wm = w & 1, wn = w >> 1;
  int lr = lane & 15, quad = lane >> 4;
  int rcol = ((quad ^ (lr >> 1)) & 3) * 8;

  for (int kt = 0; kt < hchunk / 32; kt++) {
#pragma unroll
    for (int j = 0; j < 2; j++) {
      gl_lds16(gA[j], lA[j]);
      gl_lds16(gB[j], lB[j]);
    }
    gA[0] += 32; gA[1] += 32; gB[0] += 32; gB[1] += 32;
    __syncthreads();
    bf16_8 af[4], bfr[4];
#pragma unroll
    for (int mt = 0; mt < 4; mt++)
      af[mt] = *(const bf16_8*)(ldsA + (wm * 64 + mt * 16 + lr) * 32 + rcol);
#pragma unroll
    for (int nt = 0; nt < 4; nt++)
      bfr[nt] = *(const bf16_8*)(ldsB + (wn * 64 + nt * 16 + lr) * 32 + rcol);
#pragma unroll
    for (int mt = 0; mt < 4; mt++)
#pragma unroll
      for (int nt = 0; nt < 4; nt++)
        acc[mt][nt] = __builtin_amdgcn_mfma_f32_16x16x32_bf16(af[mt], bfr[nt], acc[mt][nt], 0, 0, 0);
    __syncthreads();
  }

#pragma unroll
  for (int mt = 0; mt < 4; mt++) {
#pragma unroll
    for (int r2 = 0; r2 < 4; r2++) {
      int row = wm * 64 + mt * 16 + quad * 4 + r2;
      if (m0 + row < ne) {
        int slot = off + m0 + row;
        int t = tok_list[slot];
        float wgt = w_list[slot];
        float* orow = out + (size_t)t * DOUT;
#pragma unroll
        for (int nt = 0; nt < 4; nt++) {
          int c = n0 + wn * 64 + nt * 16 + lr;
          atomicAdd(orow + c, wgt * acc[mt][nt][r2]);
        }
      }
    }
  }
}

// ---------------- host ------------------------------------------------------
extern "C" void kernel_launch(void* const* d_in, const int* in_sizes, int n_in,
                              void* d_out, int out_size, void* d_ws, size_t ws_size,
                              hipStream_t stream) {
  const float* x  = (const float*)d_in[0];
  const float* Wg = (const float*)d_in[1];
  const float* bg = (const float*)d_in[2];
  const float* W1 = (const float*)d_in[3];
  const float* b1 = (const float*)d_in[4];
  const float* W2 = (const float*)d_in[5];
  const float* b2 = (const float*)d_in[6];
  float* out = (float*)d_out;

  char* p = (char*)d_ws;
  int*   counts   = (int*)p;   p += 256;
  int*   offsets  = (int*)p;   p += 256;
  int*   mblk_off = (int*)p;   p += 256;
  int*   topi     = (int*)p;   p += 16384 * 4;
  float* topw     = (float*)p; p += 16384 * 4;
  int*   pos      = (int*)p;   p += 16384 * 4;
  int*   tok_list = (int*)p;   p += 16384 * 4;
  float* w_list   = (float*)p; p += 16384 * 4;
  bf16*  xb       = (bf16*)p;  p += (size_t)NTOK * DIN * 2;

  size_t fixedBytes = (size_t)(p - (char*)d_ws);
  // per-hchunk bytes: h (16384+128 rows) + W1t + W2t = 33024 + 16384 + 16384 = 65792
  int hchunk = 2048;
  while (hchunk > 128 && fixedBytes + (size_t)hchunk * 65792 > ws_size) hchunk >>= 1;

  bf16* W1t  = (bf16*)p; p += (size_t)NE * hchunk * DIN * 2;
  bf16* W2t  = (bf16*)p; p += (size_t)NE * DOUT * hchunk * 2;
  bf16* hbuf = (bf16*)p; p += (size_t)(16384 + 128) * hchunk * 2;

  hipMemsetAsync(counts, 0, 32, stream);
  gate_kernel<<<NTOK / 4, 256, 0, stream>>>(x, Wg, bg, counts, topi, topw, pos);
  cvtx_kernel<<<(NTOK * DIN) / (8 * 256), 256, 0, stream>>>(x, xb);
  scan_kernel<<<1, 64, 0, stream>>>(counts, offsets, mblk_off);
  pack_kernel<<<64, 256, 0, stream>>>(topi, topw, pos, offsets, tok_list, w_list);
  init_out_kernel<<<NTOK, 256, 0, stream>>>(topi, topw, b2, out);

  int nchunks = DH / hchunk;
  for (int c = 0; c < nchunks; c++) {
    int hc0 = c * hchunk;
    // W1t[e][n][k] = W1[e][k][hc0+n]  (k rows: 1024, n cols: hchunk)
    tcvt_kernel<<<dim3(DIN / 32, hchunk / 32, NE), 256, 0, stream>>>(
        W1 + hc0, W1t, DH, (long long)DIN * DH, DIN, (long long)hchunk * DIN);
    // W2t[e][o][hk] = W2[e][hc0+hk][o] (hk rows: hchunk, o cols: 1024)
    tcvt_kernel<<<dim3(hchunk / 32, DOUT / 32, NE), 256, 0, stream>>>(
        W2 + (size_t)hc0 * DOUT, W2t, DOUT, (long long)DH * DOUT, hchunk, (long long)DOUT * hchunk);
    gemm1_kernel<<<dim3(hchunk / 128, MAXMB), 256, 0, stream>>>(
        xb, W1t, b1, counts, offsets, mblk_off, tok_list, hbuf, hchunk, hc0);
    gemm2_kernel<<<dim3(DOUT / 128, MAXMB), 256, 0, stream>>>(
        hbuf, W2t, counts, offsets, mblk_off, tok_list, w_list, out, hchunk);
  }
}

// Round 3
// 900.686 us; speedup vs baseline: 1.5514x; 1.1916x over previous
//
#include <hip/hip_runtime.h>
#include <hip/hip_bf16.h>
#include <stdint.h>

#define NTOK 8192
#define NE 8
#define DIN 1024
#define DH 4096
#define DOUT 1024
#define MAXMB 135  // max total m-blocks: 16384/128 + 7 partial tails

typedef __bf16 bf16;
typedef __bf16 bf16_8 __attribute__((ext_vector_type(8)));
typedef __bf16 bf16_4 __attribute__((ext_vector_type(4)));
typedef float f32_4 __attribute__((ext_vector_type(4)));

__device__ __forceinline__ void gl_lds16(const void* g, void* l) {
  __builtin_amdgcn_global_load_lds(
      (const __attribute__((address_space(1))) unsigned int*)g,
      (__attribute__((address_space(3))) unsigned int*)l, 16, 0, 0);
}

// ---------------- gating: fp32 logits, top-2, softmax (NO atomics) ----------
__global__ void gate_kernel(const float* __restrict__ x, const float* __restrict__ Wg,
                            const float* __restrict__ bg,
                            int* __restrict__ topi, float* __restrict__ topw) {
  int t = blockIdx.x * 4 + (threadIdx.x >> 6);
  int lane = threadIdx.x & 63;
  float acc[NE];
#pragma unroll
  for (int e = 0; e < NE; e++) acc[e] = 0.f;
  const float* xr = x + (size_t)t * DIN;
#pragma unroll
  for (int i = 0; i < DIN / 64; i++) {
    float xv = xr[lane + 64 * i];
    const float4* wr = (const float4*)(Wg + (size_t)(lane + 64 * i) * NE);
    float4 w0 = wr[0], w1 = wr[1];
    acc[0] += xv * w0.x; acc[1] += xv * w0.y; acc[2] += xv * w0.z; acc[3] += xv * w0.w;
    acc[4] += xv * w1.x; acc[5] += xv * w1.y; acc[6] += xv * w1.z; acc[7] += xv * w1.w;
  }
#pragma unroll
  for (int off = 32; off > 0; off >>= 1)
#pragma unroll
    for (int e = 0; e < NE; e++) acc[e] += __shfl_xor(acc[e], off, 64);
  if (lane == 0) {
    float lg[NE];
#pragma unroll
    for (int e = 0; e < NE; e++) lg[e] = acc[e] + bg[e];
    int i0 = 0; float v0 = lg[0];
#pragma unroll
    for (int e = 1; e < NE; e++) if (lg[e] > v0) { v0 = lg[e]; i0 = e; }
    int i1 = -1; float v1 = -3.0e38f;
#pragma unroll
    for (int e = 0; e < NE; e++) if (e != i0 && lg[e] > v1) { v1 = lg[e]; i1 = e; }
    float ex = expf(v1 - v0);
    float w0 = 1.f / (1.f + ex);
    float w1 = ex / (1.f + ex);
    topi[2 * t] = i0; topi[2 * t + 1] = i1;
    topw[2 * t] = w0; topw[2 * t + 1] = w1;
  }
}

// ---------------- histogram: block-aggregated positions ---------------------
// 64 blocks x 256 entries: LDS bins -> 8 global atomics/block -> per-entry pos
__global__ void hist_kernel(const int* __restrict__ topi, int* __restrict__ counts,
                            int* __restrict__ pos) {
  __shared__ int bins[NE];
  __shared__ int base[NE];
  int tid = threadIdx.x;
  if (tid < NE) bins[tid] = 0;
  __syncthreads();
  int i = blockIdx.x * 256 + tid;  // < 16384
  int e = topi[i];
  int local = atomicAdd(&bins[e], 1);
  __syncthreads();
  if (tid < NE) base[tid] = atomicAdd(&counts[tid], bins[tid]);
  __syncthreads();
  pos[i] = base[e] + local;
}

// offsets[e]: token-slot prefix; mblk_off[e]: m-block prefix (for grid compaction)
__global__ void scan_kernel(const int* counts, int* offsets, int* mblk_off) {
  if (threadIdx.x == 0) {
    int s = 0, b = 0;
    for (int e = 0; e < NE; e++) {
      offsets[e] = s; mblk_off[e] = b;
      s += counts[e]; b += (counts[e] + 127) >> 7;
    }
    mblk_off[NE] = b;
  }
}

__global__ void pack_kernel(const int* __restrict__ topi, const float* __restrict__ topw,
                            const int* __restrict__ pos, const int* __restrict__ offsets,
                            int* __restrict__ tok_list, float* __restrict__ w_list) {
  int i = blockIdx.x * 256 + threadIdx.x;  // < 16384
  int e = topi[i];
  int slot = offsets[e] + pos[i];
  tok_list[slot] = i >> 1;
  w_list[slot] = topw[i];
}

// ---------------- x fp32 -> bf16 --------------------------------------------
__global__ void cvtx_kernel(const float* __restrict__ x, bf16* __restrict__ xb) {
  size_t i = ((size_t)blockIdx.x * 256 + threadIdx.x) * 8;
  float4 a = *(const float4*)(x + i);
  float4 b = *(const float4*)(x + i + 4);
  bf16_8 o;
  o[0] = (bf16)a.x; o[1] = (bf16)a.y; o[2] = (bf16)a.z; o[3] = (bf16)a.w;
  o[4] = (bf16)b.x; o[5] = (bf16)b.y; o[6] = (bf16)b.z; o[7] = (bf16)b.w;
  *(bf16_8*)(xb + i) = o;
}

// ---------------- out init: out[t] = w0*b2[e0] + w1*b2[e1] ------------------
__global__ void init_out_kernel(const int* __restrict__ topi, const float* __restrict__ topw,
                                const float* __restrict__ b2, float* __restrict__ out) {
  int t = blockIdx.x;
  int c = threadIdx.x * 4;
  int e0 = topi[2 * t], e1 = topi[2 * t + 1];
  float w0 = topw[2 * t], w1 = topw[2 * t + 1];
  float4 v0 = *(const float4*)(b2 + (size_t)e0 * DOUT + c);
  float4 v1 = *(const float4*)(b2 + (size_t)e1 * DOUT + c);
  float4 o;
  o.x = w0 * v0.x + w1 * v1.x;
  o.y = w0 * v0.y + w1 * v1.y;
  o.z = w0 * v0.z + w1 * v1.z;
  o.w = w0 * v0.w + w1 * v1.w;
  *(float4*)(out + (size_t)t * DOUT + c) = o;
}

// ---------------- transpose + fp32->bf16: dst[n][k] = src[k][n] -------------
__global__ void tcvt_kernel(const float* __restrict__ src, bf16* __restrict__ dst,
                            int src_ld, long long src_es, int dst_ld, long long dst_es) {
  __shared__ bf16 tile[32][33];
  const float* s = src + blockIdx.z * src_es + (size_t)(blockIdx.x * 32) * src_ld + blockIdx.y * 32;
  bf16* d = dst + blockIdx.z * dst_es + (size_t)(blockIdx.y * 32) * dst_ld + blockIdx.x * 32;
  int tid = threadIdx.x;
  int r = tid >> 3, c4 = (tid & 7) * 4;
  float4 v = *(const float4*)(s + (size_t)r * src_ld + c4);
  tile[r][c4] = (bf16)v.x; tile[r][c4 + 1] = (bf16)v.y;
  tile[r][c4 + 2] = (bf16)v.z; tile[r][c4 + 3] = (bf16)v.w;
  __syncthreads();
  int n = tid >> 3, k4 = (tid & 7) * 4;
  bf16_4 o;
  o[0] = tile[k4][n]; o[1] = tile[k4 + 1][n]; o[2] = tile[k4 + 2][n]; o[3] = tile[k4 + 3][n];
  *(bf16_4*)(d + (size_t)n * dst_ld + k4) = o;
}

// Bank-conflict swizzle: within each 64B LDS row (4 x 16B cols), col' = col ^ ((row&15)>>1) & 3.
// Gather side: lane l in a segment stages global col ((l&3)^(l>>3))&3 of row l>>2,
// keeping lane->LDS contiguity for global_load_lds.

// ---------------- GEMM1: h = relu(gather(xb) @ W1t^T + b1) ------------------
// tiles: BM=128, BN=128, BK=32; 256 thr = 4 waves in 2x2; mfma 16x16x32 bf16
__global__ __launch_bounds__(256) void gemm1_kernel(
    const bf16* __restrict__ xb, const bf16* __restrict__ W1t,
    const float* __restrict__ b1, const int* __restrict__ counts,
    const int* __restrict__ offsets, const int* __restrict__ mblk_off,
    const int* __restrict__ tok_list,
    bf16* __restrict__ h, int hchunk, int hc0) {
  int mb = blockIdx.y;
  if (mb >= mblk_off[NE]) return;
  int e = 0;
  while (mb >= mblk_off[e + 1]) e++;
  int ne = counts[e];
  int m0 = (mb - mblk_off[e]) * 128;
  int off = offsets[e];
  int n0 = blockIdx.x * 128;

  __shared__ bf16 ldsA[128 * 32];
  __shared__ bf16 ldsB[128 * 32];

  int tid = threadIdx.x;
  int w = tid >> 6, lane = tid & 63;
  int scol = (((lane & 3) ^ (lane >> 3)) & 3) * 8;  // swizzled 16B col for staging

  const bf16* gA[2]; const bf16* gB[2];
  bf16* lA[2]; bf16* lB[2];
#pragma unroll
  for (int j = 0; j < 2; j++) {
    int seg = w * 2 + j;
    int row = seg * 16 + (lane >> 2);
    int slot = off + m0 + row;
    int smax = off + ne - 1;
    if (slot > smax) slot = smax;           // clamp tail rows to a valid token
    int tok = tok_list[slot];
    gA[j] = xb + (size_t)tok * DIN + scol;
    lA[j] = ldsA + seg * 512;               // wave-uniform base; HW adds lane*16B
    gB[j] = W1t + ((size_t)e * hchunk + n0 + row) * DIN + scol;
    lB[j] = ldsB + seg * 512;
  }

  f32_4 acc[4][4];
#pragma unroll
  for (int i = 0; i < 4; i++)
#pragma unroll
    for (int j = 0; j < 4; j++) acc[i][j] = (f32_4){0.f, 0.f, 0.f, 0.f};

  int wm = w & 1, wn = w >> 1;
  int lr = lane & 15, quad = lane >> 4;
  int rcol = ((quad ^ (lr >> 1)) & 3) * 8;

  for (int kt = 0; kt < DIN / 32; kt++) {
#pragma unroll
    for (int j = 0; j < 2; j++) {
      gl_lds16(gA[j], lA[j]);
      gl_lds16(gB[j], lB[j]);
    }
    gA[0] += 32; gA[1] += 32; gB[0] += 32; gB[1] += 32;
    __syncthreads();
    bf16_8 af[4], bfr[4];
#pragma unroll
    for (int mt = 0; mt < 4; mt++)
      af[mt] = *(const bf16_8*)(ldsA + (wm * 64 + mt * 16 + lr) * 32 + rcol);
#pragma unroll
    for (int nt = 0; nt < 4; nt++)
      bfr[nt] = *(const bf16_8*)(ldsB + (wn * 64 + nt * 16 + lr) * 32 + rcol);
#pragma unroll
    for (int mt = 0; mt < 4; mt++)
#pragma unroll
      for (int nt = 0; nt < 4; nt++)
        acc[mt][nt] = __builtin_amdgcn_mfma_f32_16x16x32_bf16(af[mt], bfr[nt], acc[mt][nt], 0, 0, 0);
    __syncthreads();
  }

#pragma unroll
  for (int nt = 0; nt < 4; nt++) {
    int cloc = wn * 64 + nt * 16 + lr;
    int c = n0 + cloc;                       // col within chunk
    float bias = b1[(size_t)e * DH + hc0 + c];
#pragma unroll
    for (int mt = 0; mt < 4; mt++) {
#pragma unroll
      for (int r2 = 0; r2 < 4; r2++) {
        int row = wm * 64 + mt * 16 + quad * 4 + r2;
        if (m0 + row < ne) {
          float v = acc[mt][nt][r2] + bias;
          v = v > 0.f ? v : 0.f;
          h[(size_t)(off + m0 + row) * hchunk + c] = (bf16)v;
        }
      }
    }
  }
}

// ---------------- GEMM2: out[tok] += w * (h @ W2t^T) ------------------------
__global__ __launch_bounds__(256) void gemm2_kernel(
    const bf16* __restrict__ h, const bf16* __restrict__ W2t,
    const int* __restrict__ counts, const int* __restrict__ offsets,
    const int* __restrict__ mblk_off, const int* __restrict__ tok_list,
    const float* __restrict__ w_list,
    float* __restrict__ out, int hchunk) {
  int mb = blockIdx.y;
  if (mb >= mblk_off[NE]) return;
  int e = 0;
  while (mb >= mblk_off[e + 1]) e++;
  int ne = counts[e];
  int m0 = (mb - mblk_off[e]) * 128;
  int off = offsets[e];
  int n0 = blockIdx.x * 128;

  __shared__ bf16 ldsA[128 * 32];
  __shared__ bf16 ldsB[128 * 32];

  int tid = threadIdx.x;
  int w = tid >> 6, lane = tid & 63;
  int scol = (((lane & 3) ^ (lane >> 3)) & 3) * 8;

  const bf16* gA[2]; const bf16* gB[2];
  bf16* lA[2]; bf16* lB[2];
#pragma unroll
  for (int j = 0; j < 2; j++) {
    int seg = w * 2 + j;
    int row = seg * 16 + (lane >> 2);
    gA[j] = h + (size_t)(off + m0 + row) * hchunk + scol;  // h padded +128 rows
    lA[j] = ldsA + seg * 512;
    gB[j] = W2t + ((size_t)e * DOUT + n0 + row) * hchunk + scol;
    lB[j] = ldsB + seg * 512;
  }

  f32_4 acc[4][4];
#pragma unroll
  for (int i = 0; i < 4; i++)
#pragma unroll
    for (int j = 0; j < 4; j++) acc[i][j] = (f32_4){0.f, 0.f, 0.f, 0.f};

  int wm = w & 1, wn = w >> 1;
  int lr = lane & 15, quad = lane >> 4;
  int rcol = ((quad ^ (lr >> 1)) & 3) * 8;

  for (int kt = 0; kt < hchunk / 32; kt++) {
#pragma unroll
    for (int j = 0; j < 2; j++) {
      gl_lds16(gA[j], lA[j]);
      gl_lds16(gB[j], lB[j]);
    }
    gA[0] += 32; gA[1] += 32; gB[0] += 32; gB[1] += 32;
    __syncthreads();
    bf16_8 af[4], bfr[4];
#pragma unroll
    for (int mt = 0; mt < 4; mt++)
      af[mt] = *(const bf16_8*)(ldsA + (wm * 64 + mt * 16 + lr) * 32 + rcol);
#pragma unroll
    for (int nt = 0; nt < 4; nt++)
      bfr[nt] = *(const bf16_8*)(ldsB + (wn * 64 + nt * 16 + lr) * 32 + rcol);
#pragma unroll
    for (int mt = 0; mt < 4; mt++)
#pragma unroll
      for (int nt = 0; nt < 4; nt++)
        acc[mt][nt] = __builtin_amdgcn_mfma_f32_16x16x32_bf16(af[mt], bfr[nt], acc[mt][nt], 0, 0, 0);
    __syncthreads();
  }

#pragma unroll
  for (int mt = 0; mt < 4; mt++) {
#pragma unroll
    for (int r2 = 0; r2 < 4; r2++) {
      int row = wm * 64 + mt * 16 + quad * 4 + r2;
      if (m0 + row < ne) {
        int slot = off + m0 + row;
        int t = tok_list[slot];
        float wgt = w_list[slot];
        float* orow = out + (size_t)t * DOUT;
#pragma unroll
        for (int nt = 0; nt < 4; nt++) {
          int c = n0 + wn * 64 + nt * 16 + lr;
          atomicAdd(orow + c, wgt * acc[mt][nt][r2]);
        }
      }
    }
  }
}

// ---------------- host ------------------------------------------------------
extern "C" void kernel_launch(void* const* d_in, const int* in_sizes, int n_in,
                              void* d_out, int out_size, void* d_ws, size_t ws_size,
                              hipStream_t stream) {
  const float* x  = (const float*)d_in[0];
  const float* Wg = (const float*)d_in[1];
  const float* bg = (const float*)d_in[2];
  const float* W1 = (const float*)d_in[3];
  const float* b1 = (const float*)d_in[4];
  const float* W2 = (const float*)d_in[5];
  const float* b2 = (const float*)d_in[6];
  float* out = (float*)d_out;

  char* p = (char*)d_ws;
  int*   counts   = (int*)p;   p += 256;
  int*   offsets  = (int*)p;   p += 256;
  int*   mblk_off = (int*)p;   p += 256;
  int*   topi     = (int*)p;   p += 16384 * 4;
  float* topw     = (float*)p; p += 16384 * 4;
  int*   pos      = (int*)p;   p += 16384 * 4;
  int*   tok_list = (int*)p;   p += 16384 * 4;
  float* w_list   = (float*)p; p += 16384 * 4;
  bf16*  xb       = (bf16*)p;  p += (size_t)NTOK * DIN * 2;

  size_t fixedBytes = (size_t)(p - (char*)d_ws);
  // per-hchunk bytes: h (16384+128 rows) + W1t + W2t = 33024 + 16384 + 16384 = 65792
  int hchunk = 2048;
  while (hchunk > 128 && fixedBytes + (size_t)hchunk * 65792 > ws_size) hchunk >>= 1;

  bf16* W1t  = (bf16*)p; p += (size_t)NE * hchunk * DIN * 2;
  bf16* W2t  = (bf16*)p; p += (size_t)NE * DOUT * hchunk * 2;
  bf16* hbuf = (bf16*)p; p += (size_t)(16384 + 128) * hchunk * 2;

  hipMemsetAsync(counts, 0, 32, stream);
  gate_kernel<<<NTOK / 4, 256, 0, stream>>>(x, Wg, bg, topi, topw);
  cvtx_kernel<<<(NTOK * DIN) / (8 * 256), 256, 0, stream>>>(x, xb);
  hist_kernel<<<64, 256, 0, stream>>>(topi, counts, pos);
  scan_kernel<<<1, 64, 0, stream>>>(counts, offsets, mblk_off);
  pack_kernel<<<64, 256, 0, stream>>>(topi, topw, pos, offsets, tok_list, w_list);
  init_out_kernel<<<NTOK, 256, 0, stream>>>(topi, topw, b2, out);

  int nchunks = DH / hchunk;
  for (int c = 0; c < nchunks; c++) {
    int hc0 = c * hchunk;
    // W1t[e][n][k] = W1[e][k][hc0+n]  (k rows: 1024, n cols: hchunk)
    tcvt_kernel<<<dim3(DIN / 32, hchunk / 32, NE), 256, 0, stream>>>(
        W1 + hc0, W1t, DH, (long long)DIN * DH, DIN, (long long)hchunk * DIN);
    // W2t[e][o][hk] = W2[e][hc0+hk][o] (hk rows: hchunk, o cols: 1024)
    tcvt_kernel<<<dim3(hchunk / 32, DOUT / 32, NE), 256, 0, stream>>>(
        W2 + (size_t)hc0 * DOUT, W2t, DOUT, (long long)DH * DOUT, hchunk, (long long)DOUT * hchunk);
    gemm1_kernel<<<dim3(hchunk / 128, MAXMB), 256, 0, stream>>>(
        xb, W1t, b1, counts, offsets, mblk_off, tok_list, hbuf, hchunk, hc0);
    gemm2_kernel<<<dim3(DOUT / 128, MAXMB), 256, 0, stream>>>(
        hbuf, W2t, counts, offsets, mblk_off, tok_list, w_list, out, hchunk);
  }
}

// Round 4
// 889.857 us; speedup vs baseline: 1.5703x; 1.0122x over previous
//
#include <hip/hip_runtime.h>
#include <hip/hip_bf16.h>
#include <stdint.h>

#define NTOK 8192
#define NE 8
#define DIN 1024
#define DH 4096
#define DOUT 1024
#define MAXMB 135  // max total m-blocks: 16384/128 + 7 partial tails

typedef __bf16 bf16;
typedef __bf16 bf16_8 __attribute__((ext_vector_type(8)));
typedef __bf16 bf16_4 __attribute__((ext_vector_type(4)));
typedef float f32_4 __attribute__((ext_vector_type(4)));

__device__ __forceinline__ void gl_lds16(const void* g, void* l) {
  __builtin_amdgcn_global_load_lds(
      (const __attribute__((address_space(1))) unsigned int*)g,
      (__attribute__((address_space(3))) unsigned int*)l, 16, 0, 0);
}

// ---------------- gating: fp32 logits, top-2, softmax (NO atomics) ----------
__global__ void gate_kernel(const float* __restrict__ x, const float* __restrict__ Wg,
                            const float* __restrict__ bg,
                            int* __restrict__ topi, float* __restrict__ topw) {
  int t = blockIdx.x * 4 + (threadIdx.x >> 6);
  int lane = threadIdx.x & 63;
  float acc[NE];
#pragma unroll
  for (int e = 0; e < NE; e++) acc[e] = 0.f;
  const float* xr = x + (size_t)t * DIN;
#pragma unroll
  for (int i = 0; i < DIN / 64; i++) {
    float xv = xr[lane + 64 * i];
    const float4* wr = (const float4*)(Wg + (size_t)(lane + 64 * i) * NE);
    float4 w0 = wr[0], w1 = wr[1];
    acc[0] += xv * w0.x; acc[1] += xv * w0.y; acc[2] += xv * w0.z; acc[3] += xv * w0.w;
    acc[4] += xv * w1.x; acc[5] += xv * w1.y; acc[6] += xv * w1.z; acc[7] += xv * w1.w;
  }
#pragma unroll
  for (int off = 32; off > 0; off >>= 1)
#pragma unroll
    for (int e = 0; e < NE; e++) acc[e] += __shfl_xor(acc[e], off, 64);
  if (lane == 0) {
    float lg[NE];
#pragma unroll
    for (int e = 0; e < NE; e++) lg[e] = acc[e] + bg[e];
    int i0 = 0; float v0 = lg[0];
#pragma unroll
    for (int e = 1; e < NE; e++) if (lg[e] > v0) { v0 = lg[e]; i0 = e; }
    int i1 = -1; float v1 = -3.0e38f;
#pragma unroll
    for (int e = 0; e < NE; e++) if (e != i0 && lg[e] > v1) { v1 = lg[e]; i1 = e; }
    float ex = expf(v1 - v0);
    float w0 = 1.f / (1.f + ex);
    float w1 = ex / (1.f + ex);
    topi[2 * t] = i0; topi[2 * t + 1] = i1;
    topw[2 * t] = w0; topw[2 * t + 1] = w1;
  }
}

// ---------------- histogram: block-aggregated positions ---------------------
__global__ void hist_kernel(const int* __restrict__ topi, int* __restrict__ counts,
                            int* __restrict__ pos) {
  __shared__ int bins[NE];
  __shared__ int base[NE];
  int tid = threadIdx.x;
  if (tid < NE) bins[tid] = 0;
  __syncthreads();
  int i = blockIdx.x * 256 + tid;  // < 16384
  int e = topi[i];
  int local = atomicAdd(&bins[e], 1);
  __syncthreads();
  if (tid < NE) base[tid] = atomicAdd(&counts[tid], bins[tid]);
  __syncthreads();
  pos[i] = base[e] + local;
}

// offsets[e]: token-slot prefix; mblk_off[e]: m-block prefix (for grid compaction)
__global__ void scan_kernel(const int* counts, int* offsets, int* mblk_off) {
  if (threadIdx.x == 0) {
    int s = 0, b = 0;
    for (int e = 0; e < NE; e++) {
      offsets[e] = s; mblk_off[e] = b;
      s += counts[e]; b += (counts[e] + 127) >> 7;
    }
    mblk_off[NE] = b;
  }
}

__global__ void pack_kernel(const int* __restrict__ topi,
                            const int* __restrict__ pos, const int* __restrict__ offsets,
                            int* __restrict__ tok_list, int* __restrict__ slot_of) {
  int i = blockIdx.x * 256 + threadIdx.x;  // < 16384
  int e = topi[i];
  int slot = offsets[e] + pos[i];
  tok_list[slot] = i >> 1;
  slot_of[i] = slot;
}

// ---------------- x fp32 -> bf16 --------------------------------------------
__global__ void cvtx_kernel(const float* __restrict__ x, bf16* __restrict__ xb) {
  size_t i = ((size_t)blockIdx.x * 256 + threadIdx.x) * 8;
  float4 a = *(const float4*)(x + i);
  float4 b = *(const float4*)(x + i + 4);
  bf16_8 o;
  o[0] = (bf16)a.x; o[1] = (bf16)a.y; o[2] = (bf16)a.z; o[3] = (bf16)a.w;
  o[4] = (bf16)b.x; o[5] = (bf16)b.y; o[6] = (bf16)b.z; o[7] = (bf16)b.w;
  *(bf16_8*)(xb + i) = o;
}

// ---------------- transpose + fp32->bf16: dst[n][k] = src[k][n] -------------
__global__ void tcvt_kernel(const float* __restrict__ src, bf16* __restrict__ dst,
                            int src_ld, long long src_es, int dst_ld, long long dst_es) {
  __shared__ bf16 tile[32][33];
  const float* s = src + blockIdx.z * src_es + (size_t)(blockIdx.x * 32) * src_ld + blockIdx.y * 32;
  bf16* d = dst + blockIdx.z * dst_es + (size_t)(blockIdx.y * 32) * dst_ld + blockIdx.x * 32;
  int tid = threadIdx.x;
  int r = tid >> 3, c4 = (tid & 7) * 4;
  float4 v = *(const float4*)(s + (size_t)r * src_ld + c4);
  tile[r][c4] = (bf16)v.x; tile[r][c4 + 1] = (bf16)v.y;
  tile[r][c4 + 2] = (bf16)v.z; tile[r][c4 + 3] = (bf16)v.w;
  __syncthreads();
  int n = tid >> 3, k4 = (tid & 7) * 4;
  bf16_4 o;
  o[0] = tile[k4][n]; o[1] = tile[k4 + 1][n]; o[2] = tile[k4 + 2][n]; o[3] = tile[k4 + 3][n];
  *(bf16_4*)(d + (size_t)n * dst_ld + k4) = o;
}

// Bank-conflict swizzle: within each 64B LDS row (4 x 16B cols), col' = col ^ ((row&15)>>1) & 3.
// Gather side: lane l in a segment stages global col ((l&3)^(l>>3))&3 of row l>>2,
// keeping lane->LDS contiguity for global_load_lds.

// ---------------- GEMM1: h = relu(gather(xb) @ W1t^T + b1) ------------------
__global__ __launch_bounds__(256) void gemm1_kernel(
    const bf16* __restrict__ xb, const bf16* __restrict__ W1t,
    const float* __restrict__ b1, const int* __restrict__ counts,
    const int* __restrict__ offsets, const int* __restrict__ mblk_off,
    const int* __restrict__ tok_list,
    bf16* __restrict__ h, int hchunk, int hc0) {
  int mb = blockIdx.y;
  if (mb >= mblk_off[NE]) return;
  int e = 0;
  while (mb >= mblk_off[e + 1]) e++;
  int ne = counts[e];
  int m0 = (mb - mblk_off[e]) * 128;
  int off = offsets[e];
  int n0 = blockIdx.x * 128;

  __shared__ bf16 ldsA[128 * 32];
  __shared__ bf16 ldsB[128 * 32];

  int tid = threadIdx.x;
  int w = tid >> 6, lane = tid & 63;
  int scol = (((lane & 3) ^ (lane >> 3)) & 3) * 8;  // swizzled 16B col for staging

  const bf16* gA[2]; const bf16* gB[2];
  bf16* lA[2]; bf16* lB[2];
#pragma unroll
  for (int j = 0; j < 2; j++) {
    int seg = w * 2 + j;
    int row = seg * 16 + (lane >> 2);
    int slot = off + m0 + row;
    int smax = off + ne - 1;
    if (slot > smax) slot = smax;           // clamp tail rows to a valid token
    int tok = tok_list[slot];
    gA[j] = xb + (size_t)tok * DIN + scol;
    lA[j] = ldsA + seg * 512;               // wave-uniform base; HW adds lane*16B
    gB[j] = W1t + ((size_t)e * hchunk + n0 + row) * DIN + scol;
    lB[j] = ldsB + seg * 512;
  }

  f32_4 acc[4][4];
#pragma unroll
  for (int i = 0; i < 4; i++)
#pragma unroll
    for (int j = 0; j < 4; j++) acc[i][j] = (f32_4){0.f, 0.f, 0.f, 0.f};

  int wm = w & 1, wn = w >> 1;
  int lr = lane & 15, quad = lane >> 4;
  int rcol = ((quad ^ (lr >> 1)) & 3) * 8;

  for (int kt = 0; kt < DIN / 32; kt++) {
#pragma unroll
    for (int j = 0; j < 2; j++) {
      gl_lds16(gA[j], lA[j]);
      gl_lds16(gB[j], lB[j]);
    }
    gA[0] += 32; gA[1] += 32; gB[0] += 32; gB[1] += 32;
    __syncthreads();
    bf16_8 af[4], bfr[4];
#pragma unroll
    for (int mt = 0; mt < 4; mt++)
      af[mt] = *(const bf16_8*)(ldsA + (wm * 64 + mt * 16 + lr) * 32 + rcol);
#pragma unroll
    for (int nt = 0; nt < 4; nt++)
      bfr[nt] = *(const bf16_8*)(ldsB + (wn * 64 + nt * 16 + lr) * 32 + rcol);
#pragma unroll
    for (int mt = 0; mt < 4; mt++)
#pragma unroll
      for (int nt = 0; nt < 4; nt++)
        acc[mt][nt] = __builtin_amdgcn_mfma_f32_16x16x32_bf16(af[mt], bfr[nt], acc[mt][nt], 0, 0, 0);
    __syncthreads();
  }

#pragma unroll
  for (int nt = 0; nt < 4; nt++) {
    int cloc = wn * 64 + nt * 16 + lr;
    int c = n0 + cloc;                       // col within chunk
    float bias = b1[(size_t)e * DH + hc0 + c];
#pragma unroll
    for (int mt = 0; mt < 4; mt++) {
#pragma unroll
      for (int r2 = 0; r2 < 4; r2++) {
        int row = wm * 64 + mt * 16 + quad * 4 + r2;
        if (m0 + row < ne) {
          float v = acc[mt][nt][r2] + bias;
          v = v > 0.f ? v : 0.f;
          h[(size_t)(off + m0 + row) * hchunk + c] = (bf16)v;
        }
      }
    }
  }
}

// ---------------- GEMM2: y[slot] (+)= h @ W2t^T  (plain stores, no atomics) -
__global__ __launch_bounds__(256) void gemm2_kernel(
    const bf16* __restrict__ h, const bf16* __restrict__ W2t,
    const int* __restrict__ counts, const int* __restrict__ offsets,
    const int* __restrict__ mblk_off,
    float* __restrict__ y, int hchunk, int accum) {
  int mb = blockIdx.y;
  if (mb >= mblk_off[NE]) return;
  int e = 0;
  while (mb >= mblk_off[e + 1]) e++;
  int ne = counts[e];
  int m0 = (mb - mblk_off[e]) * 128;
  int off = offsets[e];
  int n0 = blockIdx.x * 128;

  __shared__ bf16 ldsA[128 * 32];
  __shared__ bf16 ldsB[128 * 32];

  int tid = threadIdx.x;
  int w = tid >> 6, lane = tid & 63;
  int scol = (((lane & 3) ^ (lane >> 3)) & 3) * 8;

  const bf16* gA[2]; const bf16* gB[2];
  bf16* lA[2]; bf16* lB[2];
#pragma unroll
  for (int j = 0; j < 2; j++) {
    int seg = w * 2 + j;
    int row = seg * 16 + (lane >> 2);
    gA[j] = h + (size_t)(off + m0 + row) * hchunk + scol;  // h padded +128 rows
    lA[j] = ldsA + seg * 512;
    gB[j] = W2t + ((size_t)e * DOUT + n0 + row) * hchunk + scol;
    lB[j] = ldsB + seg * 512;
  }

  f32_4 acc[4][4];
#pragma unroll
  for (int i = 0; i < 4; i++)
#pragma unroll
    for (int j = 0; j < 4; j++) acc[i][j] = (f32_4){0.f, 0.f, 0.f, 0.f};

  int wm = w & 1, wn = w >> 1;
  int lr = lane & 15, quad = lane >> 4;
  int rcol = ((quad ^ (lr >> 1)) & 3) * 8;

  for (int kt = 0; kt < hchunk / 32; kt++) {
#pragma unroll
    for (int j = 0; j < 2; j++) {
      gl_lds16(gA[j], lA[j]);
      gl_lds16(gB[j], lB[j]);
    }
    gA[0] += 32; gA[1] += 32; gB[0] += 32; gB[1] += 32;
    __syncthreads();
    bf16_8 af[4], bfr[4];
#pragma unroll
    for (int mt = 0; mt < 4; mt++)
      af[mt] = *(const bf16_8*)(ldsA + (wm * 64 + mt * 16 + lr) * 32 + rcol);
#pragma unroll
    for (int nt = 0; nt < 4; nt++)
      bfr[nt] = *(const bf16_8*)(ldsB + (wn * 64 + nt * 16 + lr) * 32 + rcol);
#pragma unroll
    for (int mt = 0; mt < 4; mt++)
#pragma unroll
      for (int nt = 0; nt < 4; nt++)
        acc[mt][nt] = __builtin_amdgcn_mfma_f32_16x16x32_bf16(af[mt], bfr[nt], acc[mt][nt], 0, 0, 0);
    __syncthreads();
  }

#pragma unroll
  for (int mt = 0; mt < 4; mt++) {
#pragma unroll
    for (int r2 = 0; r2 < 4; r2++) {
      int row = wm * 64 + mt * 16 + quad * 4 + r2;
      if (m0 + row < ne) {
        float* yrow = y + (size_t)(off + m0 + row) * DOUT + n0;
#pragma unroll
        for (int nt = 0; nt < 4; nt++) {
          int c = wn * 64 + nt * 16 + lr;
          float v = acc[mt][nt][r2];
          if (accum) v += yrow[c];
          yrow[c] = v;
        }
      }
    }
  }
}

// ---------------- combine: out[t] = sum_k w_k * (y[slot_k] + b2[e_k]) -------
__global__ void combine_kernel(const int* __restrict__ topi, const float* __restrict__ topw,
                               const int* __restrict__ slot_of, const float* __restrict__ y,
                               const float* __restrict__ b2, float* __restrict__ out) {
  int t = blockIdx.x;
  int c = threadIdx.x * 4;
  int e0 = topi[2 * t], e1 = topi[2 * t + 1];
  float w0 = topw[2 * t], w1 = topw[2 * t + 1];
  int s0 = slot_of[2 * t], s1 = slot_of[2 * t + 1];
  float4 a = *(const float4*)(y + (size_t)s0 * DOUT + c);
  float4 b = *(const float4*)(y + (size_t)s1 * DOUT + c);
  float4 p = *(const float4*)(b2 + (size_t)e0 * DOUT + c);
  float4 q = *(const float4*)(b2 + (size_t)e1 * DOUT + c);
  float4 o;
  o.x = w0 * (a.x + p.x) + w1 * (b.x + q.x);
  o.y = w0 * (a.y + p.y) + w1 * (b.y + q.y);
  o.z = w0 * (a.z + p.z) + w1 * (b.z + q.z);
  o.w = w0 * (a.w + p.w) + w1 * (b.w + q.w);
  *(float4*)(out + (size_t)t * DOUT + c) = o;
}

// ---------------- host ------------------------------------------------------
extern "C" void kernel_launch(void* const* d_in, const int* in_sizes, int n_in,
                              void* d_out, int out_size, void* d_ws, size_t ws_size,
                              hipStream_t stream) {
  const float* x  = (const float*)d_in[0];
  const float* Wg = (const float*)d_in[1];
  const float* bg = (const float*)d_in[2];
  const float* W1 = (const float*)d_in[3];
  const float* b1 = (const float*)d_in[4];
  const float* W2 = (const float*)d_in[5];
  const float* b2 = (const float*)d_in[6];
  float* out = (float*)d_out;

  char* p = (char*)d_ws;
  int*   counts   = (int*)p;   p += 256;
  int*   offsets  = (int*)p;   p += 256;
  int*   mblk_off = (int*)p;   p += 256;
  int*   topi     = (int*)p;   p += 16384 * 4;
  float* topw     = (float*)p; p += 16384 * 4;
  int*   pos      = (int*)p;   p += 16384 * 4;
  int*   tok_list = (int*)p;   p += 16384 * 4;
  int*   slot_of  = (int*)p;   p += 16384 * 4;
  bf16*  xb       = (bf16*)p;  p += (size_t)NTOK * DIN * 2;
  float* y        = (float*)p; p += (size_t)16384 * DOUT * 4;  // 67 MB

  size_t fixedBytes = (size_t)(p - (char*)d_ws);
  // per-hchunk bytes: h (16384+128 rows)*2 + W1t 8*1024*2 + W2t 8*1024*2 = 65792
  int hchunk = 4096;
  while (hchunk > 128 && fixedBytes + (size_t)hchunk * 65792 > ws_size) hchunk >>= 1;

  bf16* W1t  = (bf16*)p; p += (size_t)NE * hchunk * DIN * 2;
  bf16* W2t  = (bf16*)p; p += (size_t)NE * DOUT * hchunk * 2;
  bf16* hbuf = (bf16*)p; p += (size_t)(16384 + 128) * hchunk * 2;

  hipMemsetAsync(counts, 0, 32, stream);
  gate_kernel<<<NTOK / 4, 256, 0, stream>>>(x, Wg, bg, topi, topw);
  cvtx_kernel<<<(NTOK * DIN) / (8 * 256), 256, 0, stream>>>(x, xb);
  hist_kernel<<<64, 256, 0, stream>>>(topi, counts, pos);
  scan_kernel<<<1, 64, 0, stream>>>(counts, offsets, mblk_off);
  pack_kernel<<<64, 256, 0, stream>>>(topi, pos, offsets, tok_list, slot_of);

  int nchunks = DH / hchunk;
  for (int c = 0; c < nchunks; c++) {
    int hc0 = c * hchunk;
    // W1t[e][n][k] = W1[e][k][hc0+n]  (k rows: 1024, n cols: hchunk)
    tcvt_kernel<<<dim3(DIN / 32, hchunk / 32, NE), 256, 0, stream>>>(
        W1 + hc0, W1t, DH, (long long)DIN * DH, DIN, (long long)hchunk * DIN);
    // W2t[e][o][hk] = W2[e][hc0+hk][o] (hk rows: hchunk, o cols: 1024)
    tcvt_kernel<<<dim3(hchunk / 32, DOUT / 32, NE), 256, 0, stream>>>(
        W2 + (size_t)hc0 * DOUT, W2t, DOUT, (long long)DH * DOUT, hchunk, (long long)DOUT * hchunk);
    gemm1_kernel<<<dim3(hchunk / 128, MAXMB), 256, 0, stream>>>(
        xb, W1t, b1, counts, offsets, mblk_off, tok_list, hbuf, hchunk, hc0);
    gemm2_kernel<<<dim3(DOUT / 128, MAXMB), 256, 0, stream>>>(
        hbuf, W2t, counts, offsets, mblk_off, y, hchunk, c > 0 ? 1 : 0);
  }
  combine_kernel<<<NTOK, 256, 0, stream>>>(topi, topw, slot_of, y, b2, out);
}